// Round 1
// baseline (544.234 us; speedup 1.0000x reference)
//
#include <hip/hip_runtime.h>
#include <hip/hip_bf16.h>

#define B_   2
#define L_   2048
#define D_   2048
#define H_   32
#define HKV_ 8
#define HD_  64
#define G_   4
#define M_   4096   // B_*L_

typedef __attribute__((ext_vector_type(8))) short bf16x8;
typedef __attribute__((ext_vector_type(4))) float f32x4;

static __device__ __forceinline__ unsigned short f2bf(float f) {
  unsigned int u = __float_as_uint(f);
  unsigned int r = (u + 0x7FFFu + ((u >> 16) & 1u)) >> 16;
  return (unsigned short)r;
}

#define GLD16(g, l) __builtin_amdgcn_global_load_lds(                      \
    (const __attribute__((address_space(1))) void*)(g),                    \
    (__attribute__((address_space(3))) void*)(l), 16, 0, 0)

// ---------------- elementwise cast f32 -> bf16 (x4 vectorized) ----------------
__global__ void cast_bf16_kernel(const float* __restrict__ in,
                                 unsigned short* __restrict__ out, int n4) {
  int i = blockIdx.x * blockDim.x + threadIdx.x;
  if (i >= n4) return;
  float4 v = ((const float4*)in)[i];
  uint2 r;
  r.x = (unsigned int)f2bf(v.x) | ((unsigned int)f2bf(v.y) << 16);
  r.y = (unsigned int)f2bf(v.z) | ((unsigned int)f2bf(v.w) << 16);
  ((uint2*)out)[i] = r;
}

// ---------------- transpose+cast: src[K][N] f32 -> dst[N][K] bf16 ----------------
__global__ void transpose_cast_kernel(const float* __restrict__ src,
                                      unsigned short* __restrict__ dst,
                                      int K, int N) {
  __shared__ float tile[32][33];
  int k0 = blockIdx.y * 32, n0 = blockIdx.x * 32;
  int tx = threadIdx.x, ty = threadIdx.y;  // (32,8)
#pragma unroll
  for (int r = 0; r < 4; ++r)
    tile[ty * 4 + r][tx] = src[(size_t)(k0 + ty * 4 + r) * N + n0 + tx];
  __syncthreads();
#pragma unroll
  for (int r = 0; r < 4; ++r)
    dst[(size_t)(n0 + ty * 4 + r) * K + k0 + tx] = f2bf(tile[tx][ty * 4 + r]);
}

// ---------------- GEMM: C[M][N] f32 = A[M][K]bf16 * Bt[N][K]bf16 ----------------
// 128x128 tile, BK=32, 4 waves (2x2 of 64x64), mfma_f32_16x16x32_bf16
__global__ __launch_bounds__(256)
void gemm_bt_kernel(const unsigned short* __restrict__ A,
                    const unsigned short* __restrict__ Bt,
                    float* __restrict__ C, int M, int N, int K) {
  __shared__ unsigned short Al[128 * 32];
  __shared__ unsigned short Bl[128 * 32];
  const int tid = threadIdx.x;
  const int w = tid >> 6;
  const int l = tid & 63;
  const int row0 = blockIdx.y * 128;
  const int col0 = blockIdx.x * 128;
  const int wr = (w >> 1) * 64, wc = (w & 1) * 64;

  f32x4 acc[4][4];
#pragma unroll
  for (int m = 0; m < 4; ++m)
#pragma unroll
    for (int n = 0; n < 4; ++n) acc[m][n] = (f32x4){0.f, 0.f, 0.f, 0.f};

  const int srow = l >> 2;          // 0..15 within 16-row chunk
  const int scol = (l & 3) * 8;     // elem offset within row (8 bf16 = 16B)
  const int fr = l & 15, fk = (l >> 4) * 8;
  const int nk = K / 32;

  for (int kt = 0; kt < nk; ++kt) {
    const int k0 = kt * 32;
#pragma unroll
    for (int t = 0; t < 2; ++t) {
      const int rr = (w * 2 + t) * 16 + srow;
      GLD16(A + (size_t)(row0 + rr) * K + k0 + scol, &Al[(w * 2 + t) * 512]);
      GLD16(Bt + (size_t)(col0 + rr) * K + k0 + scol, &Bl[(w * 2 + t) * 512]);
    }
    __syncthreads();
    bf16x8 af[4], bfr[4];
#pragma unroll
    for (int m = 0; m < 4; ++m)
      af[m] = *(const bf16x8*)&Al[(wr + m * 16 + fr) * 32 + fk];
#pragma unroll
    for (int n = 0; n < 4; ++n)
      bfr[n] = *(const bf16x8*)&Bl[(wc + n * 16 + fr) * 32 + fk];
#pragma unroll
    for (int m = 0; m < 4; ++m)
#pragma unroll
      for (int n = 0; n < 4; ++n)
        acc[m][n] = __builtin_amdgcn_mfma_f32_16x16x32_bf16(af[m], bfr[n], acc[m][n], 0, 0, 0);
    __syncthreads();
  }

  const int fq = l >> 4;
#pragma unroll
  for (int m = 0; m < 4; ++m)
#pragma unroll
    for (int n = 0; n < 4; ++n)
#pragma unroll
      for (int j = 0; j < 4; ++j) {
        int r = row0 + wr + m * 16 + fq * 4 + j;
        int c = col0 + wc + n * 16 + fr;
        C[(size_t)r * N + c] = acc[m][n][j];
      }
}

// ---------------- RoPE: src[B*L][nh*64] f32 -> dst[B][nh][L][64] bf16 ----------------
__global__ void rope_kernel(const float* __restrict__ src,
                            const float* __restrict__ cosf,
                            const float* __restrict__ sinf,
                            unsigned short* __restrict__ dst, int nh, int total) {
  int idx = blockIdx.x * blockDim.x + threadIdx.x;
  if (idx >= total) return;
  int i = idx & 31;                 // freq index
  int h = (idx >> 5) & (nh - 1);    // nh is power of 2
  int row = idx / (nh << 5);        // b*L + l
  int lpos = row & (L_ - 1);
  int b = row >> 11;
  const float* s = src + (size_t)row * (nh * 64) + h * 64 + 2 * i;
  float tr = s[0], ti = s[1];
  float c = cosf[lpos * 32 + i], sn = sinf[lpos * 32 + i];
  float orr = tr * c - ti * sn;
  float oii = tr * sn + ti * c;
  size_t o = (((size_t)(b * nh + h)) * L_ + lpos) * 64 + 2 * i;
  unsigned int packed = (unsigned int)f2bf(orr) | ((unsigned int)f2bf(oii) << 16);
  *(unsigned int*)&dst[o] = packed;
}

// ---------------- V transpose: v[B*L][HKV*64] f32 -> vT[B][HKV][64][L] bf16 ----------------
__global__ void cast_vT_kernel(const float* __restrict__ v,
                               unsigned short* __restrict__ vT, int total) {
  int idx = blockIdx.x * blockDim.x + threadIdx.x;
  if (idx >= total) return;
  int lpos = idx & (L_ - 1);
  int d = (idx >> 11) & 63;
  int hkv = (idx >> 17) & 7;
  int b = idx >> 20;
  vT[idx] = f2bf(v[((size_t)(b * L_ + lpos)) * (HKV_ * 64) + hkv * 64 + d]);
}

// ---------------- Flash attention: per (b,h,q-block-64), 4 waves x 16 rows ----------------
__global__ __launch_bounds__(256)
void attn_kernel(const unsigned short* __restrict__ Q,   // [B][H][L][64]
                 const unsigned short* __restrict__ Kt,  // [B][HKV][L][64]
                 const unsigned short* __restrict__ Vt,  // [B][HKV][64][L]
                 unsigned short* __restrict__ O) {       // [B*L][H*64]
  __shared__ unsigned short Kl[64 * 64];
  __shared__ unsigned short Vl[64 * 64];
  __shared__ unsigned short Pl[64 * 64];
  const int tid = threadIdx.x, w = tid >> 6, l = tid & 63;
  const int bh = blockIdx.x;           // b*H + h
  const int b = bh >> 5, h = bh & 31;
  const int hkv = h >> 2;              // G=4
  const int q0 = blockIdx.y * 64;

  const unsigned short* qbase =
      Q + (((size_t)bh) * L_ + q0 + w * 16 + (l & 15)) * 64 + (l >> 4) * 8;
  bf16x8 qf[2];
  qf[0] = *(const bf16x8*)(qbase);
  qf[1] = *(const bf16x8*)(qbase + 32);

  const unsigned short* kbase = Kt + ((size_t)(b * HKV_ + hkv)) * L_ * 64;
  const unsigned short* vbase = Vt + ((size_t)(b * HKV_ + hkv)) * 64 * L_;

  float m_i[4], l_i[4];
  f32x4 oacc[4];
#pragma unroll
  for (int j = 0; j < 4; ++j) { m_i[j] = -1e30f; l_i[j] = 0.f; }
#pragma unroll
  for (int nf = 0; nf < 4; ++nf) oacc[nf] = (f32x4){0.f, 0.f, 0.f, 0.f};

  const int nt = (q0 >> 6) + 1;  // causal: skip tiles fully above diagonal
  const int srow = l >> 3, scol8 = (l & 7) * 8;
  const int rbase = q0 + w * 16 + ((l >> 4) << 2);
  const int fr = l & 15, fk = (l >> 4) * 8;

  for (int t = 0; t < nt; ++t) {
    const int kv0 = t * 64;
#pragma unroll
    for (int u = 0; u < 2; ++u) {
      const int rr = (w * 2 + u) * 8 + srow;
      GLD16(kbase + ((size_t)(kv0 + rr)) * 64 + scol8, &Kl[(w * 2 + u) * 512]);
      GLD16(vbase + ((size_t)rr) * L_ + kv0 + scol8, &Vl[(w * 2 + u) * 512]);
    }
    __syncthreads();

    // S = Q K^T (16 rows x 64 cols per wave)
    f32x4 sacc[4];
#pragma unroll
    for (int nf = 0; nf < 4; ++nf) sacc[nf] = (f32x4){0.f, 0.f, 0.f, 0.f};
#pragma unroll
    for (int ks = 0; ks < 2; ++ks) {
#pragma unroll
      for (int nf = 0; nf < 4; ++nf) {
        bf16x8 kfrag = *(const bf16x8*)&Kl[(nf * 16 + fr) * 64 + ks * 32 + fk];
        sacc[nf] = __builtin_amdgcn_mfma_f32_16x16x32_bf16(qf[ks], kfrag, sacc[nf], 0, 0, 0);
      }
    }

    // online softmax
    float sv[4][4];
#pragma unroll
    for (int nf = 0; nf < 4; ++nf)
#pragma unroll
      for (int j = 0; j < 4; ++j) {
        float s = sacc[nf][j] * 0.125f;
        if (kv0 + nf * 16 + fr > rbase + j) s = -1e30f;  // causal mask
        sv[nf][j] = s;
      }
#pragma unroll
    for (int j = 0; j < 4; ++j) {
      float mx = fmaxf(fmaxf(sv[0][j], sv[1][j]), fmaxf(sv[2][j], sv[3][j]));
      mx = fmaxf(mx, __shfl_xor(mx, 1));
      mx = fmaxf(mx, __shfl_xor(mx, 2));
      mx = fmaxf(mx, __shfl_xor(mx, 4));
      mx = fmaxf(mx, __shfl_xor(mx, 8));
      float mnew = fmaxf(m_i[j], mx);
      float cr = __expf(m_i[j] - mnew);
      m_i[j] = mnew;
      float psum = 0.f;
#pragma unroll
      for (int nf = 0; nf < 4; ++nf) {
        float pp = __expf(sv[nf][j] - mnew);
        sv[nf][j] = pp;
        psum += pp;
      }
      psum += __shfl_xor(psum, 1);
      psum += __shfl_xor(psum, 2);
      psum += __shfl_xor(psum, 4);
      psum += __shfl_xor(psum, 8);
      l_i[j] = l_i[j] * cr + psum;
#pragma unroll
      for (int nf = 0; nf < 4; ++nf) oacc[nf][j] *= cr;
      // write P strip (own wave's rows only -> no barrier needed)
#pragma unroll
      for (int nf = 0; nf < 4; ++nf)
        Pl[(w * 16 + ((l >> 4) << 2) + j) * 64 + nf * 16 + fr] = f2bf(sv[nf][j]);
    }

    // O += P V   (A = P[q][kv], B = Vt[d][kv])
#pragma unroll
    for (int ks = 0; ks < 2; ++ks) {
      bf16x8 pa = *(const bf16x8*)&Pl[(w * 16 + fr) * 64 + ks * 32 + fk];
#pragma unroll
      for (int nf = 0; nf < 4; ++nf) {
        bf16x8 vfrag = *(const bf16x8*)&Vl[(nf * 16 + fr) * 64 + ks * 32 + fk];
        oacc[nf] = __builtin_amdgcn_mfma_f32_16x16x32_bf16(pa, vfrag, oacc[nf], 0, 0, 0);
      }
    }
    __syncthreads();
  }

  const int fq = l >> 4;
#pragma unroll
  for (int nf = 0; nf < 4; ++nf)
#pragma unroll
    for (int j = 0; j < 4; ++j) {
      int qrow = q0 + w * 16 + fq * 4 + j;
      int d = nf * 16 + fr;
      float val = oacc[nf][j] / l_i[j];
      O[((size_t)(b * L_ + qrow)) * 2048 + h * 64 + d] = f2bf(val);
    }
}

extern "C" void kernel_launch(void* const* d_in, const int* in_sizes, int n_in,
                              void* d_out, int out_size, void* d_ws, size_t ws_size,
                              hipStream_t stream) {
  (void)in_sizes; (void)n_in; (void)out_size; (void)ws_size;
  const float* x  = (const float*)d_in[0];
  const float* wq = (const float*)d_in[1];
  const float* wk = (const float*)d_in[2];
  const float* wv = (const float*)d_in[3];
  const float* wo = (const float*)d_in[4];
  const float* fc = (const float*)d_in[5];
  const float* fs = (const float*)d_in[6];
  float* out = (float*)d_out;

  char* ws = (char*)d_ws;
  unsigned short* x_b  = (unsigned short*)(ws + 0);           // 16 MiB
  unsigned short* wqT  = (unsigned short*)(ws + 16777216);    // 8 MiB
  unsigned short* wkT  = (unsigned short*)(ws + 25165824);    // 2 MiB
  unsigned short* wvT  = (unsigned short*)(ws + 27262976);    // 2 MiB
  unsigned short* woT  = (unsigned short*)(ws + 29360128);    // 8 MiB
  float* q_f           = (float*)(ws + 37748736);             // 32 MiB
  float* k_f           = (float*)(ws + 71303168);             // 8 MiB
  float* v_f           = (float*)(ws + 79691776);             // 8 MiB
  unsigned short* q_b  = (unsigned short*)(ws + 88080384);    // 16 MiB
  unsigned short* k_b  = (unsigned short*)(ws + 104857600);   // 4 MiB
  unsigned short* vT_b = (unsigned short*)(ws + 109051904);   // 4 MiB
  unsigned short* at_b = (unsigned short*)(ws + 37748736);    // reuse q_f region

  dim3 tb(32, 8);
  cast_bf16_kernel<<<8192, 256, 0, stream>>>(x, x_b, M_ * D_ / 4);
  transpose_cast_kernel<<<dim3(64, 64), tb, 0, stream>>>(wq, wqT, 2048, 2048);
  transpose_cast_kernel<<<dim3(16, 64), tb, 0, stream>>>(wk, wkT, 2048, 512);
  transpose_cast_kernel<<<dim3(16, 64), tb, 0, stream>>>(wv, wvT, 2048, 512);
  transpose_cast_kernel<<<dim3(64, 64), tb, 0, stream>>>(wo, woT, 2048, 2048);

  gemm_bt_kernel<<<dim3(16, 32), 256, 0, stream>>>(x_b, wqT, q_f, M_, 2048, 2048);
  gemm_bt_kernel<<<dim3(4, 32), 256, 0, stream>>>(x_b, wkT, k_f, M_, 512, 2048);
  gemm_bt_kernel<<<dim3(4, 32), 256, 0, stream>>>(x_b, wvT, v_f, M_, 512, 2048);

  rope_kernel<<<16384, 256, 0, stream>>>(q_f, fc, fs, q_b, 32, M_ * 32 * 32);
  rope_kernel<<<4096, 256, 0, stream>>>(k_f, fc, fs, k_b, 8, M_ * 8 * 32);
  cast_vT_kernel<<<8192, 256, 0, stream>>>(v_f, vT_b, B_ * HKV_ * 64 * L_);

  attn_kernel<<<dim3(64, 32), 256, 0, stream>>>(q_b, k_b, vT_b, at_b);

  gemm_bt_kernel<<<dim3(16, 32), 256, 0, stream>>>(at_b, woT, out, M_, 2048, 2048);
}

// Round 2
// 445.783 us; speedup vs baseline: 1.2209x; 1.2209x over previous
//
#include <hip/hip_runtime.h>
#include <hip/hip_bf16.h>

#define B_   2
#define L_   2048
#define D_   2048
#define H_   32
#define HKV_ 8
#define HD_  64
#define G_   4
#define M_   4096   // B_*L_
#define NF_  3072   // fused QKV output width

typedef __attribute__((ext_vector_type(8))) short bf16x8;
typedef __attribute__((ext_vector_type(4))) float f32x4;

static __device__ __forceinline__ unsigned short f2bf(float f) {
  unsigned int u = __float_as_uint(f);
  unsigned int r = (u + 0x7FFFu + ((u >> 16) & 1u)) >> 16;
  return (unsigned short)r;
}

#define GLD16(g, l) __builtin_amdgcn_global_load_lds(                      \
    (const __attribute__((address_space(1))) void*)(g),                    \
    (__attribute__((address_space(3))) void*)(l), 16, 0, 0)

// ---------------- elementwise cast f32 -> bf16 (x4 vectorized) ----------------
__global__ void cast_bf16_kernel(const float* __restrict__ in,
                                 unsigned short* __restrict__ out, int n4) {
  int i = blockIdx.x * blockDim.x + threadIdx.x;
  if (i >= n4) return;
  float4 v = ((const float4*)in)[i];
  uint2 r;
  r.x = (unsigned int)f2bf(v.x) | ((unsigned int)f2bf(v.y) << 16);
  r.y = (unsigned int)f2bf(v.z) | ((unsigned int)f2bf(v.w) << 16);
  ((uint2*)out)[i] = r;
}

// ---------------- transpose+cast: src[K][N] f32 -> dst[N][K] bf16 ----------------
__global__ void transpose_cast_kernel(const float* __restrict__ src,
                                      unsigned short* __restrict__ dst,
                                      int K, int N) {
  __shared__ float tile[32][33];
  int k0 = blockIdx.y * 32, n0 = blockIdx.x * 32;
  int tx = threadIdx.x, ty = threadIdx.y;  // (32,8)
#pragma unroll
  for (int r = 0; r < 4; ++r)
    tile[ty * 4 + r][tx] = src[(size_t)(k0 + ty * 4 + r) * N + n0 + tx];
  __syncthreads();
#pragma unroll
  for (int r = 0; r < 4; ++r)
    dst[(size_t)(n0 + ty * 4 + r) * K + k0 + tx] = f2bf(tile[tx][ty * 4 + r]);
}

// ---------------- GEMM: C[M][N] f32 = A[M][K]bf16 * Bt[N][K]bf16 ----------------
__global__ __launch_bounds__(256)
void gemm_bt_kernel(const unsigned short* __restrict__ A,
                    const unsigned short* __restrict__ Bt,
                    float* __restrict__ C, int M, int N, int K) {
  __shared__ unsigned short Al[128 * 32];
  __shared__ unsigned short Bl[128 * 32];
  const int tid = threadIdx.x;
  const int w = tid >> 6;
  const int l = tid & 63;
  const int row0 = blockIdx.y * 128;
  const int col0 = blockIdx.x * 128;
  const int wr = (w >> 1) * 64, wc = (w & 1) * 64;

  f32x4 acc[4][4];
#pragma unroll
  for (int m = 0; m < 4; ++m)
#pragma unroll
    for (int n = 0; n < 4; ++n) acc[m][n] = (f32x4){0.f, 0.f, 0.f, 0.f};

  const int srow = l >> 2;
  const int scol = (l & 3) * 8;
  const int fr = l & 15, fk = (l >> 4) * 8;
  const int nk = K / 32;

  for (int kt = 0; kt < nk; ++kt) {
    const int k0 = kt * 32;
#pragma unroll
    for (int t = 0; t < 2; ++t) {
      const int rr = (w * 2 + t) * 16 + srow;
      GLD16(A + (size_t)(row0 + rr) * K + k0 + scol, &Al[(w * 2 + t) * 512]);
      GLD16(Bt + (size_t)(col0 + rr) * K + k0 + scol, &Bl[(w * 2 + t) * 512]);
    }
    __syncthreads();
    bf16x8 af[4], bfr[4];
#pragma unroll
    for (int m = 0; m < 4; ++m)
      af[m] = *(const bf16x8*)&Al[(wr + m * 16 + fr) * 32 + fk];
#pragma unroll
    for (int n = 0; n < 4; ++n)
      bfr[n] = *(const bf16x8*)&Bl[(wc + n * 16 + fr) * 32 + fk];
#pragma unroll
    for (int m = 0; m < 4; ++m)
#pragma unroll
      for (int n = 0; n < 4; ++n)
        acc[m][n] = __builtin_amdgcn_mfma_f32_16x16x32_bf16(af[m], bfr[n], acc[m][n], 0, 0, 0);
    __syncthreads();
  }

  const int fq = l >> 4;
#pragma unroll
  for (int m = 0; m < 4; ++m)
#pragma unroll
    for (int n = 0; n < 4; ++n)
#pragma unroll
      for (int j = 0; j < 4; ++j) {
        int r = row0 + wr + m * 16 + fq * 4 + j;
        int c = col0 + wc + n * 16 + fr;
        C[(size_t)r * N + c] = acc[m][n][j];
      }
}

// ---------------- RoPE: src[M][3072] f32 (+col_off) -> dst[B][nh][L][64] bf16 ----------------
__global__ void rope_kernel(const float* __restrict__ src,
                            const float* __restrict__ cosf,
                            const float* __restrict__ sinf,
                            unsigned short* __restrict__ dst, int nh, int col_off,
                            int total) {
  int idx = blockIdx.x * blockDim.x + threadIdx.x;
  if (idx >= total) return;
  int i = idx & 31;
  int h = (idx >> 5) & (nh - 1);
  int row = idx / (nh << 5);
  int lpos = row & (L_ - 1);
  int b = row >> 11;
  const float* s = src + (size_t)row * NF_ + col_off + h * 64 + 2 * i;
  float tr = s[0], ti = s[1];
  float c = cosf[lpos * 32 + i], sn = sinf[lpos * 32 + i];
  float orr = tr * c - ti * sn;
  float oii = tr * sn + ti * c;
  size_t o = (((size_t)(b * nh + h)) * L_ + lpos) * 64 + 2 * i;
  unsigned int packed = (unsigned int)f2bf(orr) | ((unsigned int)f2bf(oii) << 16);
  *(unsigned int*)&dst[o] = packed;
}

// ---------------- V transpose (LDS-tiled): qkv_f v-cols -> vT[B][HKV][64][L] bf16 ----------------
__global__ void cast_vT_kernel(const float* __restrict__ v,
                               unsigned short* __restrict__ vT) {
  __shared__ float tile[32][33];
  int l0 = blockIdx.x * 32, d0 = blockIdx.y * 32;
  int z = blockIdx.z;                 // b*8+hkv
  int b = z >> 3, hkv = z & 7;
  int tx = threadIdx.x, ty = threadIdx.y;  // (32,8)
  const float* src = v + (size_t)(b * L_) * NF_ + 2560 + hkv * 64;
#pragma unroll
  for (int r = 0; r < 4; ++r)
    tile[ty * 4 + r][tx] = src[(size_t)(l0 + ty * 4 + r) * NF_ + d0 + tx];
  __syncthreads();
  unsigned short* dst = vT + ((size_t)z * 64) * L_;
#pragma unroll
  for (int r = 0; r < 4; ++r)
    dst[(size_t)(d0 + ty * 4 + r) * L_ + l0 + tx] = f2bf(tile[tx][ty * 4 + r]);
}

// ---------------- Flash attention: per (b,h, 128-row q-block), 4 waves x 2 strips ----------------
// LDS tiles XOR-swizzled: phys 16B-granule = logical granule ^ (row&7).
// global_load_lds writes linearly -> pre-swizzle the GLOBAL source column.
__global__ __launch_bounds__(256)
void attn_kernel(const unsigned short* __restrict__ Q,   // [B][H][L][64]
                 const unsigned short* __restrict__ Kt,  // [B][HKV][L][64]
                 const unsigned short* __restrict__ Vt,  // [B][HKV][64][L]
                 unsigned short* __restrict__ O) {       // [B*L][H*64]
  __shared__ unsigned short Kl[64 * 64];
  __shared__ unsigned short Vl[64 * 64];
  __shared__ unsigned short Pl[64 * 64];
  const int tid = threadIdx.x, w = tid >> 6, l = tid & 63;
  const int bh = blockIdx.x;
  const int b = bh >> 5, h = bh & 31;
  const int hkv = h >> 2;
  const int by = blockIdx.y;
  const int q0 = by * 128;
  const int fr = l & 15, hi = l >> 4;       // fragment row / k-group
  const int frx = fr & 7;                   // XOR key for reads

  // staging: chunk = 8 rows x 128B; source column pre-swizzled
  const int srow = l >> 3;
  const int scole = ((l & 7) ^ srow) * 8;   // swizzled element col of this lane's 16B

  const unsigned short* kbase = Kt + ((size_t)(b * HKV_ + hkv)) * L_ * 64;
  const unsigned short* vbase = Vt + ((size_t)(b * HKV_ + hkv)) * 64 * L_;

  // Q fragments: 2 strips of 16 rows per wave
  bf16x8 qf[2][2];
#pragma unroll
  for (int s = 0; s < 2; ++s) {
    const unsigned short* qb =
        Q + (((size_t)bh) * L_ + q0 + s * 64 + w * 16 + fr) * 64 + hi * 8;
    qf[s][0] = *(const bf16x8*)(qb);
    qf[s][1] = *(const bf16x8*)(qb + 32);
  }

  float m_i[2][4], l_i[2][4];
  f32x4 oacc[2][4];
#pragma unroll
  for (int s = 0; s < 2; ++s)
#pragma unroll
    for (int j = 0; j < 4; ++j) { m_i[s][j] = -1e30f; l_i[s][j] = 0.f; }
#pragma unroll
  for (int s = 0; s < 2; ++s)
#pragma unroll
    for (int nf = 0; nf < 4; ++nf) oacc[s][nf] = (f32x4){0.f, 0.f, 0.f, 0.f};

  const int nt = 2 * by + 2;

  for (int t = 0; t < nt; ++t) {
    const int kv0 = t * 64;
#pragma unroll
    for (int u = 0; u < 2; ++u) {
      const int c = w * 2 + u;
      const int rr = c * 8 + srow;
      GLD16(kbase + ((size_t)(kv0 + rr)) * 64 + scole, &Kl[c * 512]);
      GLD16(vbase + ((size_t)rr) * L_ + kv0 + scole, &Vl[c * 512]);
    }
    __syncthreads();

#pragma unroll
    for (int s = 0; s < 2; ++s) {
      if (t > 2 * by + s) continue;  // strip fully masked (uniform per block)

      // S = Q K^T
      f32x4 sacc[4];
#pragma unroll
      for (int nf = 0; nf < 4; ++nf) sacc[nf] = (f32x4){0.f, 0.f, 0.f, 0.f};
#pragma unroll
      for (int ks = 0; ks < 2; ++ks) {
#pragma unroll
        for (int nf = 0; nf < 4; ++nf) {
          bf16x8 kfrag = *(const bf16x8*)
              &Kl[(nf * 16 + fr) * 64 + (((ks * 4 + hi) ^ frx) * 8)];
          sacc[nf] = __builtin_amdgcn_mfma_f32_16x16x32_bf16(qf[s][ks], kfrag, sacc[nf], 0, 0, 0);
        }
      }

      // mask + online softmax
      const int rbase = q0 + s * 64 + w * 16 + hi * 4;
      float sv[4][4];
#pragma unroll
      for (int nf = 0; nf < 4; ++nf)
#pragma unroll
        for (int j = 0; j < 4; ++j) {
          float sval = sacc[nf][j] * 0.125f;
          if (kv0 + nf * 16 + fr > rbase + j) sval = -1e30f;
          sv[nf][j] = sval;
        }
#pragma unroll
      for (int j = 0; j < 4; ++j) {
        float mx = fmaxf(fmaxf(sv[0][j], sv[1][j]), fmaxf(sv[2][j], sv[3][j]));
        mx = fmaxf(mx, __shfl_xor(mx, 1));
        mx = fmaxf(mx, __shfl_xor(mx, 2));
        mx = fmaxf(mx, __shfl_xor(mx, 4));
        mx = fmaxf(mx, __shfl_xor(mx, 8));
        float mnew = fmaxf(m_i[s][j], mx);
        float cr = __expf(m_i[s][j] - mnew);
        m_i[s][j] = mnew;
        float psum = 0.f;
#pragma unroll
        for (int nf = 0; nf < 4; ++nf) {
          float pp = __expf(sv[nf][j] - mnew);
          sv[nf][j] = pp;
          psum += pp;
        }
        psum += __shfl_xor(psum, 1);
        psum += __shfl_xor(psum, 2);
        psum += __shfl_xor(psum, 4);
        psum += __shfl_xor(psum, 8);
        l_i[s][j] = l_i[s][j] * cr + psum;
#pragma unroll
        for (int nf = 0; nf < 4; ++nf) oacc[s][nf][j] *= cr;
        // P write, swizzled (wave-local rows only)
        const int prow = w * 16 + hi * 4 + j;
#pragma unroll
        for (int nf = 0; nf < 4; ++nf)
          Pl[prow * 64 + (((nf * 2 + (fr >> 3)) ^ (prow & 7)) * 8) + frx] =
              f2bf(sv[nf][j]);
      }

      // O += P V
#pragma unroll
      for (int ks = 0; ks < 2; ++ks) {
        bf16x8 pa = *(const bf16x8*)
            &Pl[(w * 16 + fr) * 64 + (((ks * 4 + hi) ^ frx) * 8)];
#pragma unroll
        for (int nf = 0; nf < 4; ++nf) {
          bf16x8 vfrag = *(const bf16x8*)
              &Vl[(nf * 16 + fr) * 64 + (((ks * 4 + hi) ^ frx) * 8)];
          oacc[s][nf] = __builtin_amdgcn_mfma_f32_16x16x32_bf16(pa, vfrag, oacc[s][nf], 0, 0, 0);
        }
      }
    }
    __syncthreads();
  }

#pragma unroll
  for (int s = 0; s < 2; ++s)
#pragma unroll
    for (int nf = 0; nf < 4; ++nf)
#pragma unroll
      for (int j = 0; j < 4; ++j) {
        int qrow = q0 + s * 64 + w * 16 + hi * 4 + j;
        int d = nf * 16 + fr;
        float val = oacc[s][nf][j] / l_i[s][j];
        O[((size_t)(b * L_ + qrow)) * 2048 + h * 64 + d] = f2bf(val);
      }
}

extern "C" void kernel_launch(void* const* d_in, const int* in_sizes, int n_in,
                              void* d_out, int out_size, void* d_ws, size_t ws_size,
                              hipStream_t stream) {
  (void)in_sizes; (void)n_in; (void)out_size; (void)ws_size;
  const float* x  = (const float*)d_in[0];
  const float* wq = (const float*)d_in[1];
  const float* wk = (const float*)d_in[2];
  const float* wv = (const float*)d_in[3];
  const float* wo = (const float*)d_in[4];
  const float* fc = (const float*)d_in[5];
  const float* fs = (const float*)d_in[6];
  float* out = (float*)d_out;

  char* ws = (char*)d_ws;
  unsigned short* x_b  = (unsigned short*)(ws + 0);           // 16 MiB
  unsigned short* wT   = (unsigned short*)(ws + 16777216);    // 12 MiB [3072][2048]
  unsigned short* woT  = (unsigned short*)(ws + 29360128);    // 8 MiB
  float* qkv_f         = (float*)(ws + 37748736);             // 48 MiB [4096][3072]
  unsigned short* at_b = (unsigned short*)(ws + 37748736);    // aliases qkv_f (safe: qkv consumed first)
  unsigned short* q_b  = (unsigned short*)(ws + 88080384);    // 16 MiB
  unsigned short* k_b  = (unsigned short*)(ws + 104857600);   // 4 MiB
  unsigned short* vT_b = (unsigned short*)(ws + 109051904);   // 4 MiB

  dim3 tb(32, 8);
  cast_bf16_kernel<<<8192, 256, 0, stream>>>(x, x_b, M_ * D_ / 4);
  transpose_cast_kernel<<<dim3(64, 64), tb, 0, stream>>>(wq, wT, 2048, 2048);
  transpose_cast_kernel<<<dim3(16, 64), tb, 0, stream>>>(wk, wT + (size_t)2048 * 2048, 2048, 512);
  transpose_cast_kernel<<<dim3(16, 64), tb, 0, stream>>>(wv, wT + (size_t)2560 * 2048, 2048, 512);
  transpose_cast_kernel<<<dim3(64, 64), tb, 0, stream>>>(wo, woT, 2048, 2048);

  gemm_bt_kernel<<<dim3(24, 32), 256, 0, stream>>>(x_b, wT, qkv_f, M_, NF_, 2048);

  rope_kernel<<<16384, 256, 0, stream>>>(qkv_f, fc, fs, q_b, 32, 0, M_ * 32 * 32);
  rope_kernel<<<4096, 256, 0, stream>>>(qkv_f, fc, fs, k_b, 8, 2048, M_ * 8 * 32);
  cast_vT_kernel<<<dim3(64, 2, 16), tb, 0, stream>>>(qkv_f, vT_b);

  attn_kernel<<<dim3(64, 16), 256, 0, stream>>>(q_b, k_b, vT_b, at_b);

  gemm_bt_kernel<<<dim3(16, 32), 256, 0, stream>>>(at_b, woT, out, M_, 2048, 2048);
}

// Round 3
// 399.050 us; speedup vs baseline: 1.3638x; 1.1171x over previous
//
#include <hip/hip_runtime.h>
#include <hip/hip_bf16.h>

#define B_   2
#define L_   2048
#define D_   2048
#define H_   32
#define HKV_ 8
#define HD_  64
#define G_   4
#define M_   4096   // B_*L_
#define NF_  3072   // fused QKV output width

typedef __attribute__((ext_vector_type(8))) short bf16x8;
typedef __attribute__((ext_vector_type(4))) float f32x4;

static __device__ __forceinline__ unsigned short f2bf(float f) {
  unsigned int u = __float_as_uint(f);
  unsigned int r = (u + 0x7FFFu + ((u >> 16) & 1u)) >> 16;
  return (unsigned short)r;
}
static __device__ __forceinline__ unsigned short f2bf_hw(float f) {
  __hip_bfloat16 h = __float2bfloat16(f);
  return *(unsigned short*)&h;
}

#define GLD16(g, l) __builtin_amdgcn_global_load_lds(                      \
    (const __attribute__((address_space(1))) void*)(g),                    \
    (__attribute__((address_space(3))) void*)(l), 16, 0, 0)

// ---------------- elementwise cast f32 -> bf16 (x4 vectorized) ----------------
__global__ void cast_bf16_kernel(const float* __restrict__ in,
                                 unsigned short* __restrict__ out, int n4) {
  int i = blockIdx.x * blockDim.x + threadIdx.x;
  if (i >= n4) return;
  float4 v = ((const float4*)in)[i];
  uint2 r;
  r.x = (unsigned int)f2bf(v.x) | ((unsigned int)f2bf(v.y) << 16);
  r.y = (unsigned int)f2bf(v.z) | ((unsigned int)f2bf(v.w) << 16);
  ((uint2*)out)[i] = r;
}

// ---------------- transpose+cast: src[K][N] f32 -> dst[N][K] bf16 ----------------
__global__ void transpose_cast_kernel(const float* __restrict__ src,
                                      unsigned short* __restrict__ dst,
                                      int K, int N) {
  __shared__ float tile[32][33];
  int k0 = blockIdx.y * 32, n0 = blockIdx.x * 32;
  int tx = threadIdx.x, ty = threadIdx.y;  // (32,8)
#pragma unroll
  for (int r = 0; r < 4; ++r)
    tile[ty * 4 + r][tx] = src[(size_t)(k0 + ty * 4 + r) * N + n0 + tx];
  __syncthreads();
#pragma unroll
  for (int r = 0; r < 4; ++r)
    dst[(size_t)(n0 + ty * 4 + r) * K + k0 + tx] = f2bf(tile[tx][ty * 4 + r]);
}

// ---------------- GEMM: C[M][N] f32 = A[M][K]bf16 * Bt[N][K]bf16 ----------------
__global__ __launch_bounds__(256)
void gemm_bt_kernel(const unsigned short* __restrict__ A,
                    const unsigned short* __restrict__ Bt,
                    float* __restrict__ C, int M, int N, int K) {
  __shared__ unsigned short Al[128 * 32];
  __shared__ unsigned short Bl[128 * 32];
  const int tid = threadIdx.x;
  const int w = tid >> 6;
  const int l = tid & 63;
  const int row0 = blockIdx.y * 128;
  const int col0 = blockIdx.x * 128;
  const int wr = (w >> 1) * 64, wc = (w & 1) * 64;

  f32x4 acc[4][4];
#pragma unroll
  for (int m = 0; m < 4; ++m)
#pragma unroll
    for (int n = 0; n < 4; ++n) acc[m][n] = (f32x4){0.f, 0.f, 0.f, 0.f};

  const int srow = l >> 2;
  const int scol = (l & 3) * 8;
  const int fr = l & 15, fk = (l >> 4) * 8;
  const int nk = K / 32;

  for (int kt = 0; kt < nk; ++kt) {
    const int k0 = kt * 32;
#pragma unroll
    for (int t = 0; t < 2; ++t) {
      const int rr = (w * 2 + t) * 16 + srow;
      GLD16(A + (size_t)(row0 + rr) * K + k0 + scol, &Al[(w * 2 + t) * 512]);
      GLD16(Bt + (size_t)(col0 + rr) * K + k0 + scol, &Bl[(w * 2 + t) * 512]);
    }
    __syncthreads();
    bf16x8 af[4], bfr[4];
#pragma unroll
    for (int m = 0; m < 4; ++m)
      af[m] = *(const bf16x8*)&Al[(wr + m * 16 + fr) * 32 + fk];
#pragma unroll
    for (int n = 0; n < 4; ++n)
      bfr[n] = *(const bf16x8*)&Bl[(wc + n * 16 + fr) * 32 + fk];
#pragma unroll
    for (int m = 0; m < 4; ++m)
#pragma unroll
      for (int n = 0; n < 4; ++n)
        acc[m][n] = __builtin_amdgcn_mfma_f32_16x16x32_bf16(af[m], bfr[n], acc[m][n], 0, 0, 0);
    __syncthreads();
  }

  const int fq = l >> 4;
#pragma unroll
  for (int m = 0; m < 4; ++m)
#pragma unroll
    for (int n = 0; n < 4; ++n)
#pragma unroll
      for (int j = 0; j < 4; ++j) {
        int r = row0 + wr + m * 16 + fq * 4 + j;
        int c = col0 + wc + n * 16 + fr;
        C[(size_t)r * N + c] = acc[m][n][j];
      }
}

// ---------------- RoPE: src[M][3072] f32 (+col_off) -> dst[B][nh][L][64] bf16 ----------------
// scale folds the attention 1/sqrt(HD) and log2(e) into Q so QK^T lands in exp2 domain.
__global__ void rope_kernel(const float* __restrict__ src,
                            const float* __restrict__ cosf,
                            const float* __restrict__ sinf,
                            unsigned short* __restrict__ dst, int nh, int col_off,
                            float scale, int total) {
  int idx = blockIdx.x * blockDim.x + threadIdx.x;
  if (idx >= total) return;
  int i = idx & 31;
  int h = (idx >> 5) & (nh - 1);
  int row = idx / (nh << 5);
  int lpos = row & (L_ - 1);
  int b = row >> 11;
  const float* s = src + (size_t)row * NF_ + col_off + h * 64 + 2 * i;
  float tr = s[0], ti = s[1];
  float c = cosf[lpos * 32 + i], sn = sinf[lpos * 32 + i];
  float orr = (tr * c - ti * sn) * scale;
  float oii = (tr * sn + ti * c) * scale;
  size_t o = (((size_t)(b * nh + h)) * L_ + lpos) * 64 + 2 * i;
  unsigned int packed = (unsigned int)f2bf(orr) | ((unsigned int)f2bf(oii) << 16);
  *(unsigned int*)&dst[o] = packed;
}

// ---------------- V transpose (LDS-tiled): qkv_f v-cols -> vT[B][HKV][64][L] bf16 ----------------
__global__ void cast_vT_kernel(const float* __restrict__ v,
                               unsigned short* __restrict__ vT) {
  __shared__ float tile[32][33];
  int l0 = blockIdx.x * 32, d0 = blockIdx.y * 32;
  int z = blockIdx.z;                 // b*8+hkv
  int b = z >> 3, hkv = z & 7;
  int tx = threadIdx.x, ty = threadIdx.y;  // (32,8)
  const float* src = v + (size_t)(b * L_) * NF_ + 2560 + hkv * 64;
#pragma unroll
  for (int r = 0; r < 4; ++r)
    tile[ty * 4 + r][tx] = src[(size_t)(l0 + ty * 4 + r) * NF_ + d0 + tx];
  __syncthreads();
  unsigned short* dst = vT + ((size_t)z * 64) * L_;
#pragma unroll
  for (int r = 0; r < 4; ++r)
    dst[(size_t)(d0 + ty * 4 + r) * L_ + l0 + tx] = f2bf(tile[tx][ty * 4 + r]);
}

// ---------------- Flash attention ----------------
// Grid (64 bh, 8 pairs). Each block processes q-blocks {pair, 15-pair} (128 rows each)
// -> exactly 34 KV-tiles per block (perfect causal load balance).
// Softmax in exp2 domain (Q pre-scaled); mask only on diagonal tile; per-lane
// deferred psum; defer-max rescale (THR=8 in log2 units -> P <= 256).
__global__ __launch_bounds__(256)
void attn_kernel(const unsigned short* __restrict__ Q,   // [B][H][L][64] (pre-scaled)
                 const unsigned short* __restrict__ Kt,  // [B][HKV][L][64]
                 const unsigned short* __restrict__ Vt,  // [B][HKV][64][L]
                 unsigned short* __restrict__ O) {       // [B*L][H*64]
  __shared__ unsigned short Kl[64 * 64];
  __shared__ unsigned short Vl[64 * 64];
  __shared__ unsigned short Pl[64 * 64];
  const int tid = threadIdx.x, w = tid >> 6, l = tid & 63;
  const int bh = blockIdx.x;
  const int b = bh >> 5, h = bh & 31;
  const int hkv = h >> 2;
  const int pair = blockIdx.y;
  const int fr = l & 15, hi = l >> 4;
  const int frx = fr & 7;

  const int srow = l >> 3;
  const int scole = ((l & 7) ^ srow) * 8;

  const unsigned short* kbase = Kt + ((size_t)(b * HKV_ + hkv)) * L_ * 64;
  const unsigned short* vbase = Vt + ((size_t)(b * HKV_ + hkv)) * 64 * L_;

  for (int half = 0; half < 2; ++half) {
    const int by = half ? (15 - pair) : pair;
    const int q0 = by * 128;

    bf16x8 qf[2][2];
#pragma unroll
    for (int s = 0; s < 2; ++s) {
      const unsigned short* qb =
          Q + (((size_t)bh) * L_ + q0 + s * 64 + w * 16 + fr) * 64 + hi * 8;
      qf[s][0] = *(const bf16x8*)(qb);
      qf[s][1] = *(const bf16x8*)(qb + 32);
    }

    float m_i[2][4], l_p[2][4];
    f32x4 oacc[2][4];
#pragma unroll
    for (int s = 0; s < 2; ++s)
#pragma unroll
      for (int j = 0; j < 4; ++j) { m_i[s][j] = -1e30f; l_p[s][j] = 0.f; }
#pragma unroll
    for (int s = 0; s < 2; ++s)
#pragma unroll
      for (int nf = 0; nf < 4; ++nf) oacc[s][nf] = (f32x4){0.f, 0.f, 0.f, 0.f};

    const int nt = 2 * by + 2;

    for (int t = 0; t < nt; ++t) {
      const int kv0 = t * 64;
#pragma unroll
      for (int u = 0; u < 2; ++u) {
        const int c = w * 2 + u;
        const int rr = c * 8 + srow;
        GLD16(kbase + ((size_t)(kv0 + rr)) * 64 + scole, &Kl[c * 512]);
        GLD16(vbase + ((size_t)rr) * L_ + kv0 + scole, &Vl[c * 512]);
      }
      __syncthreads();

#pragma unroll
      for (int s = 0; s < 2; ++s) {
        const int dlim = 2 * by + s;
        if (t > dlim) continue;  // strip fully masked (uniform)

        // S = Q K^T (already in exp2 domain)
        f32x4 sacc[4];
#pragma unroll
        for (int nf = 0; nf < 4; ++nf) sacc[nf] = (f32x4){0.f, 0.f, 0.f, 0.f};
#pragma unroll
        for (int ks = 0; ks < 2; ++ks) {
#pragma unroll
          for (int nf = 0; nf < 4; ++nf) {
            bf16x8 kfrag = *(const bf16x8*)
                &Kl[(nf * 16 + fr) * 64 + (((ks * 4 + hi) ^ frx) * 8)];
            sacc[nf] = __builtin_amdgcn_mfma_f32_16x16x32_bf16(qf[s][ks], kfrag, sacc[nf], 0, 0, 0);
          }
        }

        // causal mask only on the diagonal tile
        if (t == dlim) {
          const int rbase = q0 + s * 64 + w * 16 + hi * 4;
#pragma unroll
          for (int nf = 0; nf < 4; ++nf)
#pragma unroll
            for (int j = 0; j < 4; ++j)
              if (kv0 + nf * 16 + fr > rbase + j) sacc[nf][j] = -1e30f;
        }

        // row maxes (4 shfl per row)
        float rowmax[4];
#pragma unroll
        for (int j = 0; j < 4; ++j) {
          float mx = fmaxf(fmaxf(sacc[0][j], sacc[1][j]),
                           fmaxf(sacc[2][j], sacc[3][j]));
          mx = fmaxf(mx, __shfl_xor(mx, 1));
          mx = fmaxf(mx, __shfl_xor(mx, 2));
          mx = fmaxf(mx, __shfl_xor(mx, 4));
          mx = fmaxf(mx, __shfl_xor(mx, 8));
          rowmax[j] = mx;
        }

        // defer-max: rescale only if some row grew beyond threshold
        float g = rowmax[0] - m_i[s][0];
        g = fmaxf(g, rowmax[1] - m_i[s][1]);
        g = fmaxf(g, rowmax[2] - m_i[s][2]);
        g = fmaxf(g, rowmax[3] - m_i[s][3]);
        if (!__all(g <= 8.f)) {
#pragma unroll
          for (int j = 0; j < 4; ++j) {
            float mnew = fmaxf(m_i[s][j], rowmax[j]);
            float cr = exp2f(m_i[s][j] - mnew);
            m_i[s][j] = mnew;
            l_p[s][j] *= cr;
#pragma unroll
            for (int nf = 0; nf < 4; ++nf) oacc[s][nf][j] *= cr;
          }
        }

        // P = exp2(S - m); per-lane partial row-sum (reduced once at the end)
#pragma unroll
        for (int j = 0; j < 4; ++j) {
          const int prow = w * 16 + hi * 4 + j;
#pragma unroll
          for (int nf = 0; nf < 4; ++nf) {
            float p = exp2f(sacc[nf][j] - m_i[s][j]);
            l_p[s][j] += p;
            Pl[prow * 64 + (((nf * 2 + (fr >> 3)) ^ (prow & 7)) * 8) + frx] =
                f2bf_hw(p);
          }
        }

        // O += P V
#pragma unroll
        for (int ks = 0; ks < 2; ++ks) {
          bf16x8 pa = *(const bf16x8*)
              &Pl[(w * 16 + fr) * 64 + (((ks * 4 + hi) ^ frx) * 8)];
#pragma unroll
          for (int nf = 0; nf < 4; ++nf) {
            bf16x8 vfrag = *(const bf16x8*)
                &Vl[(nf * 16 + fr) * 64 + (((ks * 4 + hi) ^ frx) * 8)];
            oacc[s][nf] = __builtin_amdgcn_mfma_f32_16x16x32_bf16(pa, vfrag, oacc[s][nf], 0, 0, 0);
          }
        }
      }
      __syncthreads();
    }

    // epilogue: reduce the deferred row-sums, normalize, store
#pragma unroll
    for (int s = 0; s < 2; ++s)
#pragma unroll
      for (int j = 0; j < 4; ++j) {
        float lsum = l_p[s][j];
        lsum += __shfl_xor(lsum, 1);
        lsum += __shfl_xor(lsum, 2);
        lsum += __shfl_xor(lsum, 4);
        lsum += __shfl_xor(lsum, 8);
        float inv = 1.0f / lsum;
#pragma unroll
        for (int nf = 0; nf < 4; ++nf) {
          int qrow = q0 + s * 64 + w * 16 + hi * 4 + j;
          int d = nf * 16 + fr;
          O[((size_t)(b * L_ + qrow)) * 2048 + h * 64 + d] =
              f2bf_hw(oacc[s][nf][j] * inv);
        }
      }
  }
}

extern "C" void kernel_launch(void* const* d_in, const int* in_sizes, int n_in,
                              void* d_out, int out_size, void* d_ws, size_t ws_size,
                              hipStream_t stream) {
  (void)in_sizes; (void)n_in; (void)out_size; (void)ws_size;
  const float* x  = (const float*)d_in[0];
  const float* wq = (const float*)d_in[1];
  const float* wk = (const float*)d_in[2];
  const float* wv = (const float*)d_in[3];
  const float* wo = (const float*)d_in[4];
  const float* fc = (const float*)d_in[5];
  const float* fs = (const float*)d_in[6];
  float* out = (float*)d_out;

  char* ws = (char*)d_ws;
  unsigned short* x_b  = (unsigned short*)(ws + 0);           // 16 MiB
  unsigned short* wT   = (unsigned short*)(ws + 16777216);    // 12 MiB [3072][2048]
  unsigned short* woT  = (unsigned short*)(ws + 29360128);    // 8 MiB
  float* qkv_f         = (float*)(ws + 37748736);             // 48 MiB [4096][3072]
  unsigned short* at_b = (unsigned short*)(ws + 37748736);    // aliases qkv_f (safe: qkv consumed first)
  unsigned short* q_b  = (unsigned short*)(ws + 88080384);    // 16 MiB
  unsigned short* k_b  = (unsigned short*)(ws + 104857600);   // 4 MiB
  unsigned short* vT_b = (unsigned short*)(ws + 109051904);   // 4 MiB

  // 0.125 (1/sqrt(64)) * log2(e): QK^T then lands directly in exp2 domain.
  const float qscale = 0.125f * 1.4426950408889634f;

  dim3 tb(32, 8);
  cast_bf16_kernel<<<8192, 256, 0, stream>>>(x, x_b, M_ * D_ / 4);
  transpose_cast_kernel<<<dim3(64, 64), tb, 0, stream>>>(wq, wT, 2048, 2048);
  transpose_cast_kernel<<<dim3(16, 64), tb, 0, stream>>>(wk, wT + (size_t)2048 * 2048, 2048, 512);
  transpose_cast_kernel<<<dim3(16, 64), tb, 0, stream>>>(wv, wT + (size_t)2560 * 2048, 2048, 512);
  transpose_cast_kernel<<<dim3(64, 64), tb, 0, stream>>>(wo, woT, 2048, 2048);

  gemm_bt_kernel<<<dim3(24, 32), 256, 0, stream>>>(x_b, wT, qkv_f, M_, NF_, 2048);

  rope_kernel<<<16384, 256, 0, stream>>>(qkv_f, fc, fs, q_b, 32, 0, qscale, M_ * 32 * 32);
  rope_kernel<<<4096, 256, 0, stream>>>(qkv_f, fc, fs, k_b, 8, 2048, 1.0f, M_ * 8 * 32);
  cast_vT_kernel<<<dim3(64, 2, 16), tb, 0, stream>>>(qkv_f, vT_b);

  attn_kernel<<<dim3(64, 8), 256, 0, stream>>>(q_b, k_b, vT_b, at_b);

  gemm_bt_kernel<<<dim3(16, 32), 256, 0, stream>>>(at_b, woT, out, M_, 2048, 2048);
}